// Round 6
// baseline (173.227 us; speedup 1.0000x reference)
//
#include <hip/hip_runtime.h>
#include <stdint.h>

#define BATCH 2
#define NSEQ 4096
#define DM 256
#define NHEAD 8
#define DH 32
#define SCALE 0.17677669529663687f    // 1/sqrt(32)
#define QPRE (SCALE * 1.44269504088896340736f)   // softmax scale+log2e folded into Wq/bq

#if __has_builtin(__builtin_amdgcn_exp2f)
#define EXP2W(x) __builtin_amdgcn_exp2f(x)
#else
#define EXP2W(x) exp2f(x)
#endif

// Explicit drain of this wave's outstanding global_load_lds DMAs.
// The 1-barrier double-buffer REQUIRES tile(it+1)'s DMA complete before the
// next barrier; the compiler is not guaranteed to model the intrinsic's LDS
// write and emit this drain itself (R15/R17/R19 corruption: short/perturbed
// schedules left the DMA in flight past the barrier).  Idempotent if the
// compiler already emits it.
#define WAIT_VM0() asm volatile("s_waitcnt vmcnt(0)" ::: "memory")

typedef unsigned short ushort_t;
typedef __attribute__((ext_vector_type(8))) short short8;   // 8 bf16
typedef __attribute__((ext_vector_type(4))) float float4v;  // MFMA C/D

__device__ __forceinline__ ushort_t f2bf(float f) {
    union { float f; uint32_t i; } x; x.f = f;
    uint32_t i = x.i;
    i += ((i >> 16) & 1u) + 0x7fffu;   // RNE
    return (ushort_t)(i >> 16);
}
__device__ __forceinline__ uint32_t rne16(float f) {
    const uint32_t i = __float_as_uint(f);
    return i + 0x7fffu + ((i >> 16) & 1u);
}
#if __has_builtin(__builtin_amdgcn_cvt_pk_bf16_f32)
typedef __bf16 bf16x2_t __attribute__((ext_vector_type(2)));
__device__ __forceinline__ uint32_t pk2(float a, float b) {
    union { bf16x2_t v; uint32_t u; } c;
    c.v = __builtin_amdgcn_cvt_pk_bf16_f32(a, b);
    return c.u;
}
#else
__device__ __forceinline__ uint32_t pk2(float a, float b) {
    return __builtin_amdgcn_perm(rne16(b), rne16(a), 0x07060302u);
}
#endif

// async global->LDS, 16B per lane (dest = wave-uniform base + lane*16)
__device__ __forceinline__ void load_lds_16B(const void* g, void* lds) {
    __builtin_amdgcn_global_load_lds(
        (const __attribute__((address_space(1))) void*)g,
        (__attribute__((address_space(3))) void*)lds, 16, 0, 0);
}

// ---------------------------------------------------------------------------
// Pack W (fp32 -> bf16) once; Wq pre-scaled by QPRE.  Wp in d_out scratch.
// ---------------------------------------------------------------------------
__global__ __launch_bounds__(256) void packw_kernel(
    const float* __restrict__ Wq, const float* __restrict__ Wk,
    const float* __restrict__ Wv, ushort_t* __restrict__ Wp)
{
    const int mat = blockIdx.x >> 5;
    const int off = (((blockIdx.x & 31) << 8) + threadIdx.x) * 8;
    const float* W = (mat == 0) ? Wq : (mat == 1) ? Wk : Wv;
    const float s  = (mat == 0) ? QPRE : 1.0f;
    float4 a = *(const float4*)(W + off);
    float4 b = *(const float4*)(W + off + 4);
    uint32_t d[4] = { pk2(a.x * s, a.y * s), pk2(a.z * s, a.w * s),
                      pk2(b.x * s, b.y * s), pk2(b.z * s, b.w * s) };
    *(uint4*)(Wp + (size_t)mat * (DM * DM) + off) = *(const uint4*)d;
}

// ---------------------------------------------------------------------------
// MFMA projection (R2-proven config: grid (256,3), acc[2][4]).
// Q,K -> [bh][n][dh]; V -> transposed [bh][dh][n'] with keys permuted per
// 32-chunk (pos quad*8+kt*4+r <-> key kt*16+quad*4+r) so fattn's S^T
// C-layout == PV A-fragment layout.
// ---------------------------------------------------------------------------
#define RST 264
__global__ __launch_bounds__(256) void proj_kernel(
    const float* __restrict__ x_q, const float* __restrict__ x_kv,
    const ushort_t* __restrict__ Wp,
    const float* __restrict__ bq, const float* __restrict__ bk,
    const float* __restrict__ bv,
    ushort_t* __restrict__ Qh, ushort_t* __restrict__ Kh,
    ushort_t* __restrict__ Vt)
{
    const int mat = blockIdx.y;
    const int n0  = blockIdx.x * 32;
    const float* x    = (mat == 0) ? x_q : x_kv;
    const ushort_t* W = Wp + (size_t)mat * (DM * DM);
    const float* bias = (mat == 0) ? bq : (mat == 1) ? bk : bv;
    const float bscale = (mat == 0) ? QPRE : 1.0f;   // bias only (Wp carries QPRE)

    __shared__ __align__(16) ushort_t xls[32 * RST];
    const int t = threadIdx.x;
    {
        const int r  = t >> 3;
        const int c0 = (t & 7) * 32;
        const float* src = x + (size_t)(n0 + r) * DM + c0;
        uint32_t d[16];
        #pragma unroll
        for (int i = 0; i < 8; i++) {
            float4 v = *(const float4*)(src + i * 4);
            d[i * 2]     = pk2(v.x, v.y);
            d[i * 2 + 1] = pk2(v.z, v.w);
        }
        uint32_t* dst = (uint32_t*)&xls[r * RST + c0];
        #pragma unroll
        for (int i = 0; i < 4; i++)
            *(uint4*)(dst + i * 4) = *(const uint4*)&d[i * 4];
    }
    __syncthreads();

    const int w    = t >> 6;
    const int l    = t & 63;
    const int lm   = l & 15;
    const int quad = l >> 4;
    const int j0   = w * 64;

    float4v acc[2][4];
    #pragma unroll
    for (int rt = 0; rt < 2; rt++)
        #pragma unroll
        for (int jt = 0; jt < 4; jt++)
            acc[rt][jt] = (float4v){0.f, 0.f, 0.f, 0.f};

    for (int kc = 0; kc < DM / 32; kc++) {
        short8 af[2];
        #pragma unroll
        for (int rt = 0; rt < 2; rt++)
            af[rt] = *(const short8*)&xls[(rt * 16 + lm) * RST + kc * 32 + quad * 8];
        #pragma unroll
        for (int jt = 0; jt < 4; jt++) {
            short8 bf = *(const short8*)(W + (size_t)(j0 + jt * 16 + lm) * DM
                                           + kc * 32 + quad * 8);
            if (mat == 2) {
                acc[0][jt] = __builtin_amdgcn_mfma_f32_16x16x32_bf16(af[0], bf, acc[0][jt], 0, 0, 0);
                acc[1][jt] = __builtin_amdgcn_mfma_f32_16x16x32_bf16(af[1], bf, acc[1][jt], 0, 0, 0);
            } else {
                acc[0][jt] = __builtin_amdgcn_mfma_f32_16x16x32_bf16(bf, af[0], acc[0][jt], 0, 0, 0);
                acc[1][jt] = __builtin_amdgcn_mfma_f32_16x16x32_bf16(bf, af[1], acc[1][jt], 0, 0, 0);
            }
        }
    }

    const int bb = n0 >> 12;
    const int cn = n0 & (NSEQ - 1);
    if (mat == 2) {
        #pragma unroll
        for (int jt = 0; jt < 4; jt++) {
            const int j  = j0 + jt * 16 + lm;
            const int h  = j >> 5, dd = j & 31;
            const int bh = bb * NHEAD + h;
            const float bj = bias[j];
            #pragma unroll
            for (int rt = 0; rt < 2; rt++) {
                union { ushort_t u[4]; uint2 v; } pk;
                #pragma unroll
                for (int r = 0; r < 4; r++) pk.u[r] = f2bf(acc[rt][jt][r] + bj);
                *(uint2*)&Vt[((size_t)bh * DH + dd) * NSEQ + cn + quad * 8 + rt * 4] = pk.v;
            }
        }
    } else {
        ushort_t* dst = (mat == 0) ? Qh : Kh;
        #pragma unroll
        for (int jt = 0; jt < 4; jt++) {
            const int jb = j0 + jt * 16 + quad * 4;
            const int h  = jb >> 5, dd0 = jb & 31;
            const int bh = bb * NHEAD + h;
            float4 b4 = *(const float4*)(bias + jb);
            #pragma unroll
            for (int rt = 0; rt < 2; rt++) {
                const int n = cn + rt * 16 + lm;
                union { ushort_t u[4]; uint2 v; } pk;
                pk.u[0] = f2bf(acc[rt][jt][0] + b4.x * bscale);
                pk.u[1] = f2bf(acc[rt][jt][1] + b4.y * bscale);
                pk.u[2] = f2bf(acc[rt][jt][2] + b4.z * bscale);
                pk.u[3] = f2bf(acc[rt][jt][3] + b4.w * bscale);
                *(uint2*)&dst[((size_t)bh * NSEQ + n) * DH + dd0] = pk.v;
            }
        }
    }
}

// ---------------------------------------------------------------------------
// R20: Flash attention, QT=1, grid 1024 (4 blocks/CU, 4 waves/SIMD) WITH the
// explicit vmcnt(0)-before-barrier fix.
//
// Root-cause theory for R15/R17/R19 corruption: this 1-barrier double-buffer
// requires DMA(it+1) complete before the NEXT barrier's readers touch that
// buffer.  The compiler's vmcnt drain at s_barrier is not guaranteed for the
// global_load_lds LDS-write side effect; QT=4/QT=2 bodies (~1300/650 cy) hid
// the ~600-900cy DMA latency by luck, QT=1's short body (~325cy) and the
// R15 hint's perturbed schedule exposed it.  WAIT_VM0() makes the invariant
// explicit (idempotent if the compiler already emitted the drain).
//
// Block = 4 waves x 16 q = 64 q on one (b,h); each wave walks ALL 4096 keys.
// Per 32-key iter: stage next 4KB tile (K 2KB + V 2KB) via global_load_lds
// (1 instr per wave), WAIT_VM0+barrier, fragments via 4 ds_read_b128/wave.
// XCD-pinned: 2 heads per XCD -> K/V (1MB) fits the XCD's 4MB L2.
// ---------------------------------------------------------------------------
#define QT 1
__global__ __launch_bounds__(256) void fattn_kernel(
    const ushort_t* __restrict__ Qh, const ushort_t* __restrict__ Kh,
    const ushort_t* __restrict__ Vt, float* __restrict__ out)
{
    const int blk  = blockIdx.x;
    const int xcd  = blk & 7;
    const int jj   = blk >> 3;                  // 0..127
    const int bh   = xcd * 2 + (jj & 1);
    const int qblk = jj >> 1;                   // 0..63
    const int b    = bh >> 3, h = bh & 7;

    const int w    = threadIdx.x >> 6;
    const int l    = threadIdx.x & 63;
    const int lm   = l & 15;
    const int quad = l >> 4;
    const int q0   = qblk * 64 + w * 16;

    // [buf][ K tile 1024 ushorts | V tile 1024 ushorts ]
    __shared__ __align__(16) ushort_t tiles[2][2048];

    const ushort_t* Qb = Qh + (size_t)bh * NSEQ * DH;
    const ushort_t* Kb = Kh + (size_t)bh * NSEQ * DH;
    const ushort_t* Vb = Vt + (size_t)bh * DH * NSEQ;

    // staging source for this wave's 1KB quarter (waves 0,1: K; 2,3: V)
    const ushort_t* gsrc;
    int gadv;
    if (w < 2) { gsrc = Kb + (size_t)(w * 16 + (l >> 2)) * DH + (l & 3) * 8;  gadv = 32 * DH; }
    else       { gsrc = Vb + (size_t)((w - 2) * 16 + (l >> 2)) * NSEQ + (l & 3) * 8; gadv = 32; }

    short8 qf[QT];
    #pragma unroll
    for (int qt = 0; qt < QT; qt++)
        qf[qt] = *(const short8*)(Qb + (size_t)(q0 + qt * 16 + lm) * DH + quad * 8);

    short8 ones;
    #pragma unroll
    for (int i = 0; i < 8; i++) ones[i] = (short)0x3F80;   // bf16 1.0

    float4v accO[QT][2], accL[QT];
    #pragma unroll
    for (int qt = 0; qt < QT; qt++) {
        accO[qt][0] = (float4v){0.f, 0.f, 0.f, 0.f};
        accO[qt][1] = (float4v){0.f, 0.f, 0.f, 0.f};
        accL[qt]    = (float4v){0.f, 0.f, 0.f, 0.f};
    }
    const float4v zero = {0.f, 0.f, 0.f, 0.f};

    // prologue: stage tile 0 into buf 0
    load_lds_16B(gsrc, &tiles[0][w * 512]);
    gsrc += gadv;

    for (int it = 0; it < NSEQ / 32; it++) {
        WAIT_VM0();                   // this wave's DMA(it) landed in LDS
        __syncthreads();              // publish tile(it) to all waves
        if (it < NSEQ / 32 - 1) {     // stage tile(it+1) into the other buf
            load_lds_16B(gsrc, &tiles[(it + 1) & 1][w * 512]);
            gsrc += gadv;
        }

        const ushort_t* Kt = &tiles[it & 1][0];
        const ushort_t* Vl = &tiles[it & 1][1024];
        short8 kf0 = *(const short8*)&Kt[lm * 32 + quad * 8];
        short8 kf1 = *(const short8*)&Kt[512 + lm * 32 + quad * 8];
        short8 vf0 = *(const short8*)&Vl[lm * 32 + quad * 8];
        short8 vf1 = *(const short8*)&Vl[512 + lm * 32 + quad * 8];

        #pragma unroll
        for (int qt = 0; qt < QT; qt++) {
            float4v s0 = __builtin_amdgcn_mfma_f32_16x16x32_bf16(kf0, qf[qt], zero, 0, 0, 0);
            float4v s1 = __builtin_amdgcn_mfma_f32_16x16x32_bf16(kf1, qf[qt], zero, 0, 0, 0);
            float p0[4], p1[4];
            #pragma unroll
            for (int r = 0; r < 4; r++) {
                p0[r] = EXP2W(s0[r]);
                p1[r] = EXP2W(s1[r]);
            }
            uint32_t pd[4] = { pk2(p0[0], p0[1]), pk2(p0[2], p0[3]),
                               pk2(p1[0], p1[1]), pk2(p1[2], p1[3]) };
            short8 pf = *(const short8*)pd;
            accO[qt][0] = __builtin_amdgcn_mfma_f32_16x16x32_bf16(pf, vf0, accO[qt][0], 0, 0, 0);
            accO[qt][1] = __builtin_amdgcn_mfma_f32_16x16x32_bf16(pf, vf1, accO[qt][1], 0, 0, 0);
            accL[qt]    = __builtin_amdgcn_mfma_f32_16x16x32_bf16(pf, ones, accL[qt], 0, 0, 0);
        }
    }

    // epilogue: accL[qt][r] = L[q0 + qt*16 + quad*4 + r] (same rows as accO)
    #pragma unroll
    for (int qt = 0; qt < QT; qt++)
        #pragma unroll
        for (int r = 0; r < 4; r++) {
            const float inv = 1.0f / accL[qt][r];
            const int q = q0 + qt * 16 + quad * 4 + r;
            float* orow = out + ((size_t)b * NSEQ + q) * DM + h * DH;
            orow[lm]      = accO[qt][0][r] * inv;
            orow[16 + lm] = accO[qt][1][r] * inv;
        }
}

// ---------------------------------------------------------------------------
extern "C" void kernel_launch(void* const* d_in, const int* in_sizes, int n_in,
                              void* d_out, int out_size, void* d_ws, size_t ws_size,
                              hipStream_t stream)
{
    const float* x_q  = (const float*)d_in[0];
    const float* x_kv = (const float*)d_in[1];
    const float* Wq   = (const float*)d_in[2];
    const float* bq   = (const float*)d_in[3];
    const float* Wk   = (const float*)d_in[4];
    const float* bk   = (const float*)d_in[5];
    const float* Wv   = (const float*)d_in[6];
    const float* bv   = (const float*)d_in[7];
    float* out = (float*)d_out;

    const size_t per = (size_t)BATCH * NHEAD * NSEQ * DH;  // 2M elems
    ushort_t* Qh = (ushort_t*)d_ws;
    ushort_t* Kh = Qh + per;
    ushort_t* Vt = Kh + per;
    ushort_t* Wp = (ushort_t*)d_out;   // scratch; fattn rewrites all of out

    packw_kernel<<<96, 256, 0, stream>>>(Wq, Wk, Wv, Wp);

    dim3 pgrid(BATCH * NSEQ / 32, 3);
    proj_kernel<<<pgrid, 256, 0, stream>>>(x_q, x_kv, Wp, bq, bk, bv,
                                           Qh, Kh, Vt);

    fattn_kernel<<<1024, 256, 0, stream>>>(Qh, Kh, Vt, out);
}

// Round 7
// 168.469 us; speedup vs baseline: 1.0282x; 1.0282x over previous
//
#include <hip/hip_runtime.h>
#include <stdint.h>

#define BATCH 2
#define NSEQ 4096
#define DM 256
#define NHEAD 8
#define DH 32
#define SCALE 0.17677669529663687f    // 1/sqrt(32)
#define QPRE (SCALE * 1.44269504088896340736f)   // softmax scale+log2e folded into Wq/bq

#if __has_builtin(__builtin_amdgcn_exp2f)
#define EXP2W(x) __builtin_amdgcn_exp2f(x)
#else
#define EXP2W(x) exp2f(x)
#endif

// Explicit drain of this wave's outstanding global_load_lds DMAs.
// The 1-barrier double-buffer REQUIRES tile(it)'s DMA complete before the
// barrier publishes it; the compiler does NOT reliably emit this drain for
// the global_load_lds LDS-write side effect (R15/R17/R19 corruption; R20
// proved the fix: QT=1 failed without it, passed with it).
#define WAIT_VM0() asm volatile("s_waitcnt vmcnt(0)" ::: "memory")

typedef unsigned short ushort_t;
typedef __attribute__((ext_vector_type(8))) short short8;   // 8 bf16
typedef __attribute__((ext_vector_type(4))) float float4v;  // MFMA C/D

__device__ __forceinline__ ushort_t f2bf(float f) {
    union { float f; uint32_t i; } x; x.f = f;
    uint32_t i = x.i;
    i += ((i >> 16) & 1u) + 0x7fffu;   // RNE
    return (ushort_t)(i >> 16);
}
__device__ __forceinline__ uint32_t rne16(float f) {
    const uint32_t i = __float_as_uint(f);
    return i + 0x7fffu + ((i >> 16) & 1u);
}
#if __has_builtin(__builtin_amdgcn_cvt_pk_bf16_f32)
typedef __bf16 bf16x2_t __attribute__((ext_vector_type(2)));
__device__ __forceinline__ uint32_t pk2(float a, float b) {
    union { bf16x2_t v; uint32_t u; } c;
    c.v = __builtin_amdgcn_cvt_pk_bf16_f32(a, b);
    return c.u;
}
#else
__device__ __forceinline__ uint32_t pk2(float a, float b) {
    return __builtin_amdgcn_perm(rne16(b), rne16(a), 0x07060302u);
}
#endif

// async global->LDS, 16B per lane (dest = wave-uniform base + lane*16)
__device__ __forceinline__ void load_lds_16B(const void* g, void* lds) {
    __builtin_amdgcn_global_load_lds(
        (const __attribute__((address_space(1))) void*)g,
        (__attribute__((address_space(3))) void*)lds, 16, 0, 0);
}

// ---------------------------------------------------------------------------
// Pack W (fp32 -> bf16) once; Wq pre-scaled by QPRE.  Wp in d_out scratch.
// ---------------------------------------------------------------------------
__global__ __launch_bounds__(256) void packw_kernel(
    const float* __restrict__ Wq, const float* __restrict__ Wk,
    const float* __restrict__ Wv, ushort_t* __restrict__ Wp)
{
    const int mat = blockIdx.x >> 5;
    const int off = (((blockIdx.x & 31) << 8) + threadIdx.x) * 8;
    const float* W = (mat == 0) ? Wq : (mat == 1) ? Wk : Wv;
    const float s  = (mat == 0) ? QPRE : 1.0f;
    float4 a = *(const float4*)(W + off);
    float4 b = *(const float4*)(W + off + 4);
    uint32_t d[4] = { pk2(a.x * s, a.y * s), pk2(a.z * s, a.w * s),
                      pk2(b.x * s, b.y * s), pk2(b.z * s, b.w * s) };
    *(uint4*)(Wp + (size_t)mat * (DM * DM) + off) = *(const uint4*)d;
}

// ---------------------------------------------------------------------------
// MFMA projection (R2-proven config: grid (256,3), acc[2][4]).
// Q,K -> [bh][n][dh]; V -> transposed [bh][dh][n'] with keys permuted per
// 32-chunk (pos quad*8+kt*4+r <-> key kt*16+quad*4+r) so fattn's S^T
// C-layout == PV A-fragment layout.
// ---------------------------------------------------------------------------
#define RST 264
__global__ __launch_bounds__(256) void proj_kernel(
    const float* __restrict__ x_q, const float* __restrict__ x_kv,
    const ushort_t* __restrict__ Wp,
    const float* __restrict__ bq, const float* __restrict__ bk,
    const float* __restrict__ bv,
    ushort_t* __restrict__ Qh, ushort_t* __restrict__ Kh,
    ushort_t* __restrict__ Vt)
{
    const int mat = blockIdx.y;
    const int n0  = blockIdx.x * 32;
    const float* x    = (mat == 0) ? x_q : x_kv;
    const ushort_t* W = Wp + (size_t)mat * (DM * DM);
    const float* bias = (mat == 0) ? bq : (mat == 1) ? bk : bv;
    const float bscale = (mat == 0) ? QPRE : 1.0f;   // bias only (Wp carries QPRE)

    __shared__ __align__(16) ushort_t xls[32 * RST];
    const int t = threadIdx.x;
    {
        const int r  = t >> 3;
        const int c0 = (t & 7) * 32;
        const float* src = x + (size_t)(n0 + r) * DM + c0;
        uint32_t d[16];
        #pragma unroll
        for (int i = 0; i < 8; i++) {
            float4 v = *(const float4*)(src + i * 4);
            d[i * 2]     = pk2(v.x, v.y);
            d[i * 2 + 1] = pk2(v.z, v.w);
        }
        uint32_t* dst = (uint32_t*)&xls[r * RST + c0];
        #pragma unroll
        for (int i = 0; i < 4; i++)
            *(uint4*)(dst + i * 4) = *(const uint4*)&d[i * 4];
    }
    __syncthreads();

    const int w    = t >> 6;
    const int l    = t & 63;
    const int lm   = l & 15;
    const int quad = l >> 4;
    const int j0   = w * 64;

    float4v acc[2][4];
    #pragma unroll
    for (int rt = 0; rt < 2; rt++)
        #pragma unroll
        for (int jt = 0; jt < 4; jt++)
            acc[rt][jt] = (float4v){0.f, 0.f, 0.f, 0.f};

    for (int kc = 0; kc < DM / 32; kc++) {
        short8 af[2];
        #pragma unroll
        for (int rt = 0; rt < 2; rt++)
            af[rt] = *(const short8*)&xls[(rt * 16 + lm) * RST + kc * 32 + quad * 8];
        #pragma unroll
        for (int jt = 0; jt < 4; jt++) {
            short8 bf = *(const short8*)(W + (size_t)(j0 + jt * 16 + lm) * DM
                                           + kc * 32 + quad * 8);
            if (mat == 2) {
                acc[0][jt] = __builtin_amdgcn_mfma_f32_16x16x32_bf16(af[0], bf, acc[0][jt], 0, 0, 0);
                acc[1][jt] = __builtin_amdgcn_mfma_f32_16x16x32_bf16(af[1], bf, acc[1][jt], 0, 0, 0);
            } else {
                acc[0][jt] = __builtin_amdgcn_mfma_f32_16x16x32_bf16(bf, af[0], acc[0][jt], 0, 0, 0);
                acc[1][jt] = __builtin_amdgcn_mfma_f32_16x16x32_bf16(bf, af[1], acc[1][jt], 0, 0, 0);
            }
        }
    }

    const int bb = n0 >> 12;
    const int cn = n0 & (NSEQ - 1);
    if (mat == 2) {
        #pragma unroll
        for (int jt = 0; jt < 4; jt++) {
            const int j  = j0 + jt * 16 + lm;
            const int h  = j >> 5, dd = j & 31;
            const int bh = bb * NHEAD + h;
            const float bj = bias[j];
            #pragma unroll
            for (int rt = 0; rt < 2; rt++) {
                union { ushort_t u[4]; uint2 v; } pk;
                #pragma unroll
                for (int r = 0; r < 4; r++) pk.u[r] = f2bf(acc[rt][jt][r] + bj);
                *(uint2*)&Vt[((size_t)bh * DH + dd) * NSEQ + cn + quad * 8 + rt * 4] = pk.v;
            }
        }
    } else {
        ushort_t* dst = (mat == 0) ? Qh : Kh;
        #pragma unroll
        for (int jt = 0; jt < 4; jt++) {
            const int jb = j0 + jt * 16 + quad * 4;
            const int h  = jb >> 5, dd0 = jb & 31;
            const int bh = bb * NHEAD + h;
            float4 b4 = *(const float4*)(bias + jb);
            #pragma unroll
            for (int rt = 0; rt < 2; rt++) {
                const int n = cn + rt * 16 + lm;
                union { ushort_t u[4]; uint2 v; } pk;
                pk.u[0] = f2bf(acc[rt][jt][0] + b4.x * bscale);
                pk.u[1] = f2bf(acc[rt][jt][1] + b4.y * bscale);
                pk.u[2] = f2bf(acc[rt][jt][2] + b4.z * bscale);
                pk.u[3] = f2bf(acc[rt][jt][3] + b4.w * bscale);
                *(uint2*)&dst[((size_t)bh * NSEQ + n) * DH + dd0] = pk.v;
            }
        }
    }
}

// ---------------------------------------------------------------------------
// Fallback flash attention: QT=2, grid 512 (proven R16 config) + WAIT_VM0.
// ---------------------------------------------------------------------------
#define QT 2
__global__ __launch_bounds__(256) void fattn_kernel(
    const ushort_t* __restrict__ Qh, const ushort_t* __restrict__ Kh,
    const ushort_t* __restrict__ Vt, float* __restrict__ out)
{
    const int blk  = blockIdx.x;
    const int xcd  = blk & 7;
    const int jj   = blk >> 3;                  // 0..63
    const int bh   = xcd * 2 + (jj & 1);
    const int qblk = jj >> 1;                   // 0..31
    const int b    = bh >> 3, h = bh & 7;

    const int w    = threadIdx.x >> 6;
    const int l    = threadIdx.x & 63;
    const int lm   = l & 15;
    const int quad = l >> 4;
    const int q0   = qblk * 128 + w * 32;

    __shared__ __align__(16) ushort_t tiles[2][2048];

    const ushort_t* Qb = Qh + (size_t)bh * NSEQ * DH;
    const ushort_t* Kb = Kh + (size_t)bh * NSEQ * DH;
    const ushort_t* Vb = Vt + (size_t)bh * DH * NSEQ;

    const ushort_t* gsrc;
    int gadv;
    if (w < 2) { gsrc = Kb + (size_t)(w * 16 + (l >> 2)) * DH + (l & 3) * 8;  gadv = 32 * DH; }
    else       { gsrc = Vb + (size_t)((w - 2) * 16 + (l >> 2)) * NSEQ + (l & 3) * 8; gadv = 32; }

    short8 qf[QT];
    #pragma unroll
    for (int qt = 0; qt < QT; qt++)
        qf[qt] = *(const short8*)(Qb + (size_t)(q0 + qt * 16 + lm) * DH + quad * 8);

    short8 ones;
    #pragma unroll
    for (int i = 0; i < 8; i++) ones[i] = (short)0x3F80;   // bf16 1.0

    float4v accO[QT][2], accL[QT];
    #pragma unroll
    for (int qt = 0; qt < QT; qt++) {
        accO[qt][0] = (float4v){0.f, 0.f, 0.f, 0.f};
        accO[qt][1] = (float4v){0.f, 0.f, 0.f, 0.f};
        accL[qt]    = (float4v){0.f, 0.f, 0.f, 0.f};
    }
    const float4v zero = {0.f, 0.f, 0.f, 0.f};

    load_lds_16B(gsrc, &tiles[0][w * 512]);
    gsrc += gadv;

    for (int it = 0; it < NSEQ / 32; it++) {
        WAIT_VM0();
        __syncthreads();
        if (it < NSEQ / 32 - 1) {
            load_lds_16B(gsrc, &tiles[(it + 1) & 1][w * 512]);
            gsrc += gadv;
        }

        const ushort_t* Kt = &tiles[it & 1][0];
        const ushort_t* Vl = &tiles[it & 1][1024];
        short8 kf0 = *(const short8*)&Kt[lm * 32 + quad * 8];
        short8 kf1 = *(const short8*)&Kt[512 + lm * 32 + quad * 8];
        short8 vf0 = *(const short8*)&Vl[lm * 32 + quad * 8];
        short8 vf1 = *(const short8*)&Vl[512 + lm * 32 + quad * 8];

        #pragma unroll
        for (int qt = 0; qt < QT; qt++) {
            float4v s0 = __builtin_amdgcn_mfma_f32_16x16x32_bf16(kf0, qf[qt], zero, 0, 0, 0);
            float4v s1 = __builtin_amdgcn_mfma_f32_16x16x32_bf16(kf1, qf[qt], zero, 0, 0, 0);
            float p0[4], p1[4];
            #pragma unroll
            for (int r = 0; r < 4; r++) {
                p0[r] = EXP2W(s0[r]);
                p1[r] = EXP2W(s1[r]);
            }
            uint32_t pd[4] = { pk2(p0[0], p0[1]), pk2(p0[2], p0[3]),
                               pk2(p1[0], p1[1]), pk2(p1[2], p1[3]) };
            short8 pf = *(const short8*)pd;
            accO[qt][0] = __builtin_amdgcn_mfma_f32_16x16x32_bf16(pf, vf0, accO[qt][0], 0, 0, 0);
            accO[qt][1] = __builtin_amdgcn_mfma_f32_16x16x32_bf16(pf, vf1, accO[qt][1], 0, 0, 0);
            accL[qt]    = __builtin_amdgcn_mfma_f32_16x16x32_bf16(pf, ones, accL[qt], 0, 0, 0);
        }
    }

    #pragma unroll
    for (int qt = 0; qt < QT; qt++)
        #pragma unroll
        for (int r = 0; r < 4; r++) {
            const float inv = 1.0f / accL[qt][r];
            const int q = q0 + qt * 16 + quad * 4 + r;
            float* orow = out + ((size_t)b * NSEQ + q) * DM + h * DH;
            orow[lm]      = accO[qt][0][r] * inv;
            orow[16 + lm] = accO[qt][1][r] * inv;
        }
}

// ---------------------------------------------------------------------------
// R21: K-split flash attention + WAIT_VM0 fix.
// QT=2 body (efficient: per-iter fixed costs amortized over 2 q-tiles) with
// grid 1024 => 4 blocks/CU.  Total wave-iterations = 4096 waves x 64 iters =
// 262K, same as the 84us QT=2 config, but at the 4-blocks/CU TLP that R20
// measured at 436 cy/block-iter (vs 787 at 2 blocks/CU).
// R19 corrupted WITHOUT the vmcnt fix; R20 proved the fix on QT=1.
// khalf in {0,1}: each block walks 2048 keys.  No running max exists (plain
// sum-of-exp2) so partials combine exactly: out = (O0+O1)/(L0+L1).
// khalf 0 writes raw O to `out`, khalf 1 to Opart; L sums to Lp.
// ---------------------------------------------------------------------------
#define KITERS 64
__global__ __launch_bounds__(256) void fattn_split_kernel(
    const ushort_t* __restrict__ Qh, const ushort_t* __restrict__ Kh,
    const ushort_t* __restrict__ Vt, float* __restrict__ out,
    float* __restrict__ Opart, float* __restrict__ Lp)
{
    const int blk  = blockIdx.x;
    const int xcd  = blk & 7;
    const int jj   = blk >> 3;                  // 0..127
    const int bh   = xcd * 2 + (jj & 1);
    const int qblk = (jj >> 1) & 31;            // 0..31
    const int khalf = jj >> 6;                  // 0..1
    const int b    = bh >> 3, h = bh & 7;

    const int w    = threadIdx.x >> 6;
    const int l    = threadIdx.x & 63;
    const int lm   = l & 15;
    const int quad = l >> 4;
    const int q0   = qblk * 128 + w * 32;

    __shared__ __align__(16) ushort_t tiles[2][2048];

    const ushort_t* Qb = Qh + (size_t)bh * NSEQ * DH;
    const ushort_t* Kb = Kh + (size_t)bh * NSEQ * DH + (size_t)khalf * 2048 * DH;
    const ushort_t* Vb = Vt + (size_t)bh * DH * NSEQ + (size_t)khalf * 2048;

    const ushort_t* gsrc;
    int gadv;
    if (w < 2) { gsrc = Kb + (size_t)(w * 16 + (l >> 2)) * DH + (l & 3) * 8;  gadv = 32 * DH; }
    else       { gsrc = Vb + (size_t)((w - 2) * 16 + (l >> 2)) * NSEQ + (l & 3) * 8; gadv = 32; }

    short8 qf[QT];
    #pragma unroll
    for (int qt = 0; qt < QT; qt++)
        qf[qt] = *(const short8*)(Qb + (size_t)(q0 + qt * 16 + lm) * DH + quad * 8);

    short8 ones;
    #pragma unroll
    for (int i = 0; i < 8; i++) ones[i] = (short)0x3F80;   // bf16 1.0

    float4v accO[QT][2], accL[QT];
    #pragma unroll
    for (int qt = 0; qt < QT; qt++) {
        accO[qt][0] = (float4v){0.f, 0.f, 0.f, 0.f};
        accO[qt][1] = (float4v){0.f, 0.f, 0.f, 0.f};
        accL[qt]    = (float4v){0.f, 0.f, 0.f, 0.f};
    }
    const float4v zero = {0.f, 0.f, 0.f, 0.f};

    load_lds_16B(gsrc, &tiles[0][w * 512]);
    gsrc += gadv;

    for (int it = 0; it < KITERS; it++) {
        WAIT_VM0();                   // this wave's DMA(it) landed in LDS
        __syncthreads();              // publish tile(it) to all waves
        if (it < KITERS - 1) {
            load_lds_16B(gsrc, &tiles[(it + 1) & 1][w * 512]);
            gsrc += gadv;
        }

        const ushort_t* Kt = &tiles[it & 1][0];
        const ushort_t* Vl = &tiles[it & 1][1024];
        short8 kf0 = *(const short8*)&Kt[lm * 32 + quad * 8];
        short8 kf1 = *(const short8*)&Kt[512 + lm * 32 + quad * 8];
        short8 vf0 = *(const short8*)&Vl[lm * 32 + quad * 8];
        short8 vf1 = *(const short8*)&Vl[512 + lm * 32 + quad * 8];

        #pragma unroll
        for (int qt = 0; qt < QT; qt++) {
            float4v s0 = __builtin_amdgcn_mfma_f32_16x16x32_bf16(kf0, qf[qt], zero, 0, 0, 0);
            float4v s1 = __builtin_amdgcn_mfma_f32_16x16x32_bf16(kf1, qf[qt], zero, 0, 0, 0);
            float p0[4], p1[4];
            #pragma unroll
            for (int r = 0; r < 4; r++) {
                p0[r] = EXP2W(s0[r]);
                p1[r] = EXP2W(s1[r]);
            }
            uint32_t pd[4] = { pk2(p0[0], p0[1]), pk2(p0[2], p0[3]),
                               pk2(p1[0], p1[1]), pk2(p1[2], p1[3]) };
            short8 pf = *(const short8*)pd;
            accO[qt][0] = __builtin_amdgcn_mfma_f32_16x16x32_bf16(pf, vf0, accO[qt][0], 0, 0, 0);
            accO[qt][1] = __builtin_amdgcn_mfma_f32_16x16x32_bf16(pf, vf1, accO[qt][1], 0, 0, 0);
            accL[qt]    = __builtin_amdgcn_mfma_f32_16x16x32_bf16(pf, ones, accL[qt], 0, 0, 0);
        }
    }

    // epilogue: raw partial sums (no divide); khalf 0 -> out, khalf 1 -> Opart
    float* Od = (khalf == 0) ? out : Opart;
    #pragma unroll
    for (int qt = 0; qt < QT; qt++)
        #pragma unroll
        for (int r = 0; r < 4; r++) {
            const int q = q0 + qt * 16 + quad * 4 + r;
            float* orow = Od + ((size_t)b * NSEQ + q) * DM + h * DH;
            orow[lm]      = accO[qt][0][r];
            orow[16 + lm] = accO[qt][1][r];
            if (lm == 0)
                Lp[khalf * (16 * NSEQ) + bh * NSEQ + q] = accL[qt][r];
        }
}

// ---------------------------------------------------------------------------
// Combine: out = (O0 + O1) / (L0 + L1).  2M floats, 8 per thread.
// ---------------------------------------------------------------------------
__global__ __launch_bounds__(256) void combine_kernel(
    float* __restrict__ out, const float* __restrict__ Opart,
    const float* __restrict__ Lp)
{
    const int t   = blockIdx.x * 256 + threadIdx.x;
    const size_t base = (size_t)t * 8;
    const int b   = (int)(base >> 20);                 // 4096*256 = 1M floats/batch
    const int rem = (int)(base & ((1u << 20) - 1));
    const int q   = rem >> 8;
    const int dm  = rem & 255;
    const int h   = dm >> 5;
    const int bh  = b * NHEAD + h;
    const float l0 = Lp[bh * NSEQ + q];
    const float l1 = Lp[16 * NSEQ + bh * NSEQ + q];
    const float inv = 1.0f / (l0 + l1);
    float4 a0 = *(const float4*)(out + base);
    float4 a1 = *(const float4*)(out + base + 4);
    float4 c0 = *(const float4*)(Opart + base);
    float4 c1 = *(const float4*)(Opart + base + 4);
    a0.x = (a0.x + c0.x) * inv;  a0.y = (a0.y + c0.y) * inv;
    a0.z = (a0.z + c0.z) * inv;  a0.w = (a0.w + c0.w) * inv;
    a1.x = (a1.x + c1.x) * inv;  a1.y = (a1.y + c1.y) * inv;
    a1.z = (a1.z + c1.z) * inv;  a1.w = (a1.w + c1.w) * inv;
    *(float4*)(out + base)     = a0;
    *(float4*)(out + base + 4) = a1;
}

// ---------------------------------------------------------------------------
extern "C" void kernel_launch(void* const* d_in, const int* in_sizes, int n_in,
                              void* d_out, int out_size, void* d_ws, size_t ws_size,
                              hipStream_t stream)
{
    const float* x_q  = (const float*)d_in[0];
    const float* x_kv = (const float*)d_in[1];
    const float* Wq   = (const float*)d_in[2];
    const float* bq   = (const float*)d_in[3];
    const float* Wk   = (const float*)d_in[4];
    const float* bk   = (const float*)d_in[5];
    const float* Wv   = (const float*)d_in[6];
    const float* bv   = (const float*)d_in[7];
    float* out = (float*)d_out;

    const size_t per = (size_t)BATCH * NHEAD * NSEQ * DH;  // 2M elems
    ushort_t* Qh = (ushort_t*)d_ws;
    ushort_t* Kh = Qh + per;
    ushort_t* Vt = Kh + per;
    ushort_t* Wp = (ushort_t*)d_out;   // scratch; fattn rewrites all of out

    // K-split partials live after QKV in the workspace
    const size_t qkv_bytes   = per * 3 * sizeof(ushort_t);            // 12.6 MB
    const size_t opart_elems = (size_t)BATCH * NSEQ * DM;             // 2M floats
    const size_t lp_elems    = (size_t)2 * 16 * NSEQ;                 // 128K floats
    const size_t need = qkv_bytes + (opart_elems + lp_elems) * sizeof(float);
    float* Opart = (float*)((char*)d_ws + qkv_bytes);
    float* Lp    = Opart + opart_elems;

    packw_kernel<<<96, 256, 0, stream>>>(Wq, Wk, Wv, Wp);

    dim3 pgrid(BATCH * NSEQ / 32, 3);
    proj_kernel<<<pgrid, 256, 0, stream>>>(x_q, x_kv, Wp, bq, bk, bv,
                                           Qh, Kh, Vt);

    if (ws_size >= need) {
        fattn_split_kernel<<<1024, 256, 0, stream>>>(Qh, Kh, Vt, out, Opart, Lp);
        combine_kernel<<<(BATCH * NSEQ * DM) / (256 * 8), 256, 0, stream>>>(out, Opart, Lp);
    } else {
        fattn_kernel<<<512, 256, 0, stream>>>(Qh, Kh, Vt, out);
    }
}

// Round 8
// 164.920 us; speedup vs baseline: 1.0504x; 1.0215x over previous
//
#include <hip/hip_runtime.h>
#include <stdint.h>

#define BATCH 2
#define NSEQ 4096
#define DM 256
#define NHEAD 8
#define DH 32
#define SCALE 0.17677669529663687f    // 1/sqrt(32)
#define QPRE (SCALE * 1.44269504088896340736f)   // softmax scale+log2e folded into Wq/bq

#if __has_builtin(__builtin_amdgcn_exp2f)
#define EXP2W(x) __builtin_amdgcn_exp2f(x)
#else
#define EXP2W(x) exp2f(x)
#endif

// Explicit drain of this wave's outstanding global_load_lds DMAs.
// The 1-barrier double-buffer REQUIRES tile(it)'s DMA complete before the
// barrier publishes it; the compiler does NOT reliably emit this drain for
// the global_load_lds LDS-write side effect (R15/R17/R19 corruption; R20
// proved the fix: QT=1 failed without it, passed with it).
#define WAIT_VM0() asm volatile("s_waitcnt vmcnt(0)" ::: "memory")

typedef unsigned short ushort_t;
typedef __attribute__((ext_vector_type(8))) short short8;   // 8 bf16
typedef __attribute__((ext_vector_type(4))) float float4v;  // MFMA C/D

__device__ __forceinline__ ushort_t f2bf(float f) {
    union { float f; uint32_t i; } x; x.f = f;
    uint32_t i = x.i;
    i += ((i >> 16) & 1u) + 0x7fffu;   // RNE
    return (ushort_t)(i >> 16);
}
__device__ __forceinline__ uint32_t rne16(float f) {
    const uint32_t i = __float_as_uint(f);
    return i + 0x7fffu + ((i >> 16) & 1u);
}
#if __has_builtin(__builtin_amdgcn_cvt_pk_bf16_f32)
typedef __bf16 bf16x2_t __attribute__((ext_vector_type(2)));
__device__ __forceinline__ uint32_t pk2(float a, float b) {
    union { bf16x2_t v; uint32_t u; } c;
    c.v = __builtin_amdgcn_cvt_pk_bf16_f32(a, b);
    return c.u;
}
#else
__device__ __forceinline__ uint32_t pk2(float a, float b) {
    return __builtin_amdgcn_perm(rne16(b), rne16(a), 0x07060302u);
}
#endif

// async global->LDS, 16B per lane (dest = wave-uniform base + lane*16)
__device__ __forceinline__ void load_lds_16B(const void* g, void* lds) {
    __builtin_amdgcn_global_load_lds(
        (const __attribute__((address_space(1))) void*)g,
        (__attribute__((address_space(3))) void*)lds, 16, 0, 0);
}

// ---------------------------------------------------------------------------
// Pack W (fp32 -> bf16) once; Wq pre-scaled by QPRE.  Wp in d_out scratch.
// ---------------------------------------------------------------------------
__global__ __launch_bounds__(256) void packw_kernel(
    const float* __restrict__ Wq, const float* __restrict__ Wk,
    const float* __restrict__ Wv, ushort_t* __restrict__ Wp)
{
    const int mat = blockIdx.x >> 5;
    const int off = (((blockIdx.x & 31) << 8) + threadIdx.x) * 8;
    const float* W = (mat == 0) ? Wq : (mat == 1) ? Wk : Wv;
    const float s  = (mat == 0) ? QPRE : 1.0f;
    float4 a = *(const float4*)(W + off);
    float4 b = *(const float4*)(W + off + 4);
    uint32_t d[4] = { pk2(a.x * s, a.y * s), pk2(a.z * s, a.w * s),
                      pk2(b.x * s, b.y * s), pk2(b.z * s, b.w * s) };
    *(uint4*)(Wp + (size_t)mat * (DM * DM) + off) = *(const uint4*)d;
}

// ---------------------------------------------------------------------------
// MFMA projection (R2-proven config: grid (256,3), acc[2][4]).
// Q,K -> [bh][n][dh]; V -> transposed [bh][dh][n'] with keys permuted per
// 32-chunk (pos quad*8+kt*4+r <-> key kt*16+quad*4+r) so fattn's S^T
// C-layout == PV A-fragment layout.
// ---------------------------------------------------------------------------
#define RST 264
__global__ __launch_bounds__(256) void proj_kernel(
    const float* __restrict__ x_q, const float* __restrict__ x_kv,
    const ushort_t* __restrict__ Wp,
    const float* __restrict__ bq, const float* __restrict__ bk,
    const float* __restrict__ bv,
    ushort_t* __restrict__ Qh, ushort_t* __restrict__ Kh,
    ushort_t* __restrict__ Vt)
{
    const int mat = blockIdx.y;
    const int n0  = blockIdx.x * 32;
    const float* x    = (mat == 0) ? x_q : x_kv;
    const ushort_t* W = Wp + (size_t)mat * (DM * DM);
    const float* bias = (mat == 0) ? bq : (mat == 1) ? bk : bv;
    const float bscale = (mat == 0) ? QPRE : 1.0f;   // bias only (Wp carries QPRE)

    __shared__ __align__(16) ushort_t xls[32 * RST];
    const int t = threadIdx.x;
    {
        const int r  = t >> 3;
        const int c0 = (t & 7) * 32;
        const float* src = x + (size_t)(n0 + r) * DM + c0;
        uint32_t d[16];
        #pragma unroll
        for (int i = 0; i < 8; i++) {
            float4 v = *(const float4*)(src + i * 4);
            d[i * 2]     = pk2(v.x, v.y);
            d[i * 2 + 1] = pk2(v.z, v.w);
        }
        uint32_t* dst = (uint32_t*)&xls[r * RST + c0];
        #pragma unroll
        for (int i = 0; i < 4; i++)
            *(uint4*)(dst + i * 4) = *(const uint4*)&d[i * 4];
    }
    __syncthreads();

    const int w    = t >> 6;
    const int l    = t & 63;
    const int lm   = l & 15;
    const int quad = l >> 4;
    const int j0   = w * 64;

    float4v acc[2][4];
    #pragma unroll
    for (int rt = 0; rt < 2; rt++)
        #pragma unroll
        for (int jt = 0; jt < 4; jt++)
            acc[rt][jt] = (float4v){0.f, 0.f, 0.f, 0.f};

    for (int kc = 0; kc < DM / 32; kc++) {
        short8 af[2];
        #pragma unroll
        for (int rt = 0; rt < 2; rt++)
            af[rt] = *(const short8*)&xls[(rt * 16 + lm) * RST + kc * 32 + quad * 8];
        #pragma unroll
        for (int jt = 0; jt < 4; jt++) {
            short8 bf = *(const short8*)(W + (size_t)(j0 + jt * 16 + lm) * DM
                                           + kc * 32 + quad * 8);
            if (mat == 2) {
                acc[0][jt] = __builtin_amdgcn_mfma_f32_16x16x32_bf16(af[0], bf, acc[0][jt], 0, 0, 0);
                acc[1][jt] = __builtin_amdgcn_mfma_f32_16x16x32_bf16(af[1], bf, acc[1][jt], 0, 0, 0);
            } else {
                acc[0][jt] = __builtin_amdgcn_mfma_f32_16x16x32_bf16(bf, af[0], acc[0][jt], 0, 0, 0);
                acc[1][jt] = __builtin_amdgcn_mfma_f32_16x16x32_bf16(bf, af[1], acc[1][jt], 0, 0, 0);
            }
        }
    }

    const int bb = n0 >> 12;
    const int cn = n0 & (NSEQ - 1);
    if (mat == 2) {
        #pragma unroll
        for (int jt = 0; jt < 4; jt++) {
            const int j  = j0 + jt * 16 + lm;
            const int h  = j >> 5, dd = j & 31;
            const int bh = bb * NHEAD + h;
            const float bj = bias[j];
            #pragma unroll
            for (int rt = 0; rt < 2; rt++) {
                union { ushort_t u[4]; uint2 v; } pk;
                #pragma unroll
                for (int r = 0; r < 4; r++) pk.u[r] = f2bf(acc[rt][jt][r] + bj);
                *(uint2*)&Vt[((size_t)bh * DH + dd) * NSEQ + cn + quad * 8 + rt * 4] = pk.v;
            }
        }
    } else {
        ushort_t* dst = (mat == 0) ? Qh : Kh;
        #pragma unroll
        for (int jt = 0; jt < 4; jt++) {
            const int jb = j0 + jt * 16 + quad * 4;
            const int h  = jb >> 5, dd0 = jb & 31;
            const int bh = bb * NHEAD + h;
            float4 b4 = *(const float4*)(bias + jb);
            #pragma unroll
            for (int rt = 0; rt < 2; rt++) {
                const int n = cn + rt * 16 + lm;
                union { ushort_t u[4]; uint2 v; } pk;
                pk.u[0] = f2bf(acc[rt][jt][0] + b4.x * bscale);
                pk.u[1] = f2bf(acc[rt][jt][1] + b4.y * bscale);
                pk.u[2] = f2bf(acc[rt][jt][2] + b4.z * bscale);
                pk.u[3] = f2bf(acc[rt][jt][3] + b4.w * bscale);
                *(uint2*)&dst[((size_t)bh * NSEQ + n) * DH + dd0] = pk.v;
            }
        }
    }
}

// ---------------------------------------------------------------------------
// Fallback flash attention: QT=2, grid 512 (proven R16 config) + WAIT_VM0.
// ---------------------------------------------------------------------------
#define QT 2
__global__ __launch_bounds__(256) void fattn_kernel(
    const ushort_t* __restrict__ Qh, const ushort_t* __restrict__ Kh,
    const ushort_t* __restrict__ Vt, float* __restrict__ out)
{
    const int blk  = blockIdx.x;
    const int xcd  = blk & 7;
    const int jj   = blk >> 3;                  // 0..63
    const int bh   = xcd * 2 + (jj & 1);
    const int qblk = jj >> 1;                   // 0..31
    const int b    = bh >> 3, h = bh & 7;

    const int w    = threadIdx.x >> 6;
    const int l    = threadIdx.x & 63;
    const int lm   = l & 15;
    const int quad = l >> 4;
    const int q0   = qblk * 128 + w * 32;

    __shared__ __align__(16) ushort_t tiles[2][2048];

    const ushort_t* Qb = Qh + (size_t)bh * NSEQ * DH;
    const ushort_t* Kb = Kh + (size_t)bh * NSEQ * DH;
    const ushort_t* Vb = Vt + (size_t)bh * DH * NSEQ;

    const ushort_t* gsrc;
    int gadv;
    if (w < 2) { gsrc = Kb + (size_t)(w * 16 + (l >> 2)) * DH + (l & 3) * 8;  gadv = 32 * DH; }
    else       { gsrc = Vb + (size_t)((w - 2) * 16 + (l >> 2)) * NSEQ + (l & 3) * 8; gadv = 32; }

    short8 qf[QT];
    #pragma unroll
    for (int qt = 0; qt < QT; qt++)
        qf[qt] = *(const short8*)(Qb + (size_t)(q0 + qt * 16 + lm) * DH + quad * 8);

    short8 ones;
    #pragma unroll
    for (int i = 0; i < 8; i++) ones[i] = (short)0x3F80;   // bf16 1.0

    float4v accO[QT][2], accL[QT];
    #pragma unroll
    for (int qt = 0; qt < QT; qt++) {
        accO[qt][0] = (float4v){0.f, 0.f, 0.f, 0.f};
        accO[qt][1] = (float4v){0.f, 0.f, 0.f, 0.f};
        accL[qt]    = (float4v){0.f, 0.f, 0.f, 0.f};
    }
    const float4v zero = {0.f, 0.f, 0.f, 0.f};

    load_lds_16B(gsrc, &tiles[0][w * 512]);
    gsrc += gadv;

    for (int it = 0; it < NSEQ / 32; it++) {
        WAIT_VM0();
        __syncthreads();
        if (it < NSEQ / 32 - 1) {
            load_lds_16B(gsrc, &tiles[(it + 1) & 1][w * 512]);
            gsrc += gadv;
        }

        const ushort_t* Kt = &tiles[it & 1][0];
        const ushort_t* Vl = &tiles[it & 1][1024];
        short8 kf0 = *(const short8*)&Kt[lm * 32 + quad * 8];
        short8 kf1 = *(const short8*)&Kt[512 + lm * 32 + quad * 8];
        short8 vf0 = *(const short8*)&Vl[lm * 32 + quad * 8];
        short8 vf1 = *(const short8*)&Vl[512 + lm * 32 + quad * 8];

        #pragma unroll
        for (int qt = 0; qt < QT; qt++) {
            float4v s0 = __builtin_amdgcn_mfma_f32_16x16x32_bf16(kf0, qf[qt], zero, 0, 0, 0);
            float4v s1 = __builtin_amdgcn_mfma_f32_16x16x32_bf16(kf1, qf[qt], zero, 0, 0, 0);
            float p0[4], p1[4];
            #pragma unroll
            for (int r = 0; r < 4; r++) {
                p0[r] = EXP2W(s0[r]);
                p1[r] = EXP2W(s1[r]);
            }
            uint32_t pd[4] = { pk2(p0[0], p0[1]), pk2(p0[2], p0[3]),
                               pk2(p1[0], p1[1]), pk2(p1[2], p1[3]) };
            short8 pf = *(const short8*)pd;
            accO[qt][0] = __builtin_amdgcn_mfma_f32_16x16x32_bf16(pf, vf0, accO[qt][0], 0, 0, 0);
            accO[qt][1] = __builtin_amdgcn_mfma_f32_16x16x32_bf16(pf, vf1, accO[qt][1], 0, 0, 0);
            accL[qt]    = __builtin_amdgcn_mfma_f32_16x16x32_bf16(pf, ones, accL[qt], 0, 0, 0);
        }
    }

    #pragma unroll
    for (int qt = 0; qt < QT; qt++)
        #pragma unroll
        for (int r = 0; r < 4; r++) {
            const float inv = 1.0f / accL[qt][r];
            const int q = q0 + qt * 16 + quad * 4 + r;
            float* orow = out + ((size_t)b * NSEQ + q) * DM + h * DH;
            orow[lm]      = accO[qt][0][r] * inv;
            orow[16 + lm] = accO[qt][1][r] * inv;
        }
}

// ---------------------------------------------------------------------------
// R22: K-split flash attention, KVBLK=64 (two 32-key chunks per barrier
// period).  R21 measured 754 cyc per 32-key block-iter with no pipe >35%
// per-SIMD: per-iteration overhead (vmcnt drain + barrier + ds_read->MFMA->
// exp->pack->MFMA ramp) dominates.  Halving the iteration count (32 iters
// of 64 keys) amortizes that overhead 2x and doubles per-iter ILP.
// This is a pure UNROLL of two verified iterations into one barrier period:
// each 32-key chunk keeps the exact proven dataflow (kf pair -> s pair ->
// 8 exps -> pf -> vf-pair MFMAs); V subtiles stay [32dh][32keys] so the
// proj key-permutation contract and bank behavior are untouched; per-
// accumulator FP order is preserved.  WAIT_VM0 fix retained (drains both
// staging DMAs).  LDS 16KB/block -> still 4 blocks/CU.
// LDS tile layout (ushorts): [ K 64x32 : 0..2047 | Va 32x32 : 2048..3071 |
//                              Vb 32x32 : 3072..4095 ]
// Staging per wave per iter: 2 x load_lds_16B (1KB each).
// ---------------------------------------------------------------------------
#define KITERS 32
__global__ __launch_bounds__(256) void fattn_split_kernel(
    const ushort_t* __restrict__ Qh, const ushort_t* __restrict__ Kh,
    const ushort_t* __restrict__ Vt, float* __restrict__ out,
    float* __restrict__ Opart, float* __restrict__ Lp)
{
    const int blk  = blockIdx.x;
    const int xcd  = blk & 7;
    const int jj   = blk >> 3;                  // 0..127
    const int bh   = xcd * 2 + (jj & 1);
    const int qblk = (jj >> 1) & 31;            // 0..31
    const int khalf = jj >> 6;                  // 0..1
    const int b    = bh >> 3, h = bh & 7;

    const int w    = threadIdx.x >> 6;
    const int l    = threadIdx.x & 63;
    const int lm   = l & 15;
    const int quad = l >> 4;
    const int q0   = qblk * 128 + w * 32;

    __shared__ __align__(16) ushort_t tiles[2][4096];

    const ushort_t* Qb = Qh + (size_t)bh * NSEQ * DH;
    const ushort_t* Kb = Kh + (size_t)bh * NSEQ * DH + (size_t)khalf * 2048 * DH;
    const ushort_t* Vb = Vt + (size_t)bh * DH * NSEQ + (size_t)khalf * 2048;

    // staging: waves 0,1 -> K (keys w*32..w*32+31); waves 2,3 -> V subtiles
    const ushort_t *gsA, *gsB;
    int dA, dB, gadv;
    if (w < 2) {
        gsA  = Kb + (size_t)(w * 32 + (l >> 2)) * DH + (l & 3) * 8;
        gsB  = gsA + 16 * DH;
        dA   = w * 1024;  dB = dA + 512;
        gadv = 64 * DH;
    } else {
        gsA  = Vb + (size_t)(l >> 2) * NSEQ + (w - 2) * 32 + (l & 3) * 8;
        gsB  = gsA + 16 * NSEQ;
        dA   = 2048 + (w - 2) * 1024;  dB = dA + 512;
        gadv = 64;
    }

    short8 qf[QT];
    #pragma unroll
    for (int qt = 0; qt < QT; qt++)
        qf[qt] = *(const short8*)(Qb + (size_t)(q0 + qt * 16 + lm) * DH + quad * 8);

    short8 ones;
    #pragma unroll
    for (int i = 0; i < 8; i++) ones[i] = (short)0x3F80;   // bf16 1.0

    float4v accO[QT][2], accL[QT];
    #pragma unroll
    for (int qt = 0; qt < QT; qt++) {
        accO[qt][0] = (float4v){0.f, 0.f, 0.f, 0.f};
        accO[qt][1] = (float4v){0.f, 0.f, 0.f, 0.f};
        accL[qt]    = (float4v){0.f, 0.f, 0.f, 0.f};
    }
    const float4v zero = {0.f, 0.f, 0.f, 0.f};

    // prologue: stage tile 0 into buf 0
    load_lds_16B(gsA, &tiles[0][dA]);
    load_lds_16B(gsB, &tiles[0][dB]);
    gsA += gadv;  gsB += gadv;

    for (int it = 0; it < KITERS; it++) {
        WAIT_VM0();                   // this wave's 2 DMAs for tile(it) landed
        __syncthreads();              // publish tile(it) to all waves
        if (it < KITERS - 1) {
            load_lds_16B(gsA, &tiles[(it + 1) & 1][dA]);
            load_lds_16B(gsB, &tiles[(it + 1) & 1][dB]);
            gsA += gadv;  gsB += gadv;
        }

        const ushort_t* Kt  = &tiles[it & 1][0];
        const ushort_t* Vla = &tiles[it & 1][2048];
        const ushort_t* Vlb = &tiles[it & 1][3072];
        short8 kf0 = *(const short8*)&Kt[lm * 32 + quad * 8];
        short8 kf1 = *(const short8*)&Kt[512 + lm * 32 + quad * 8];
        short8 kf2 = *(const short8*)&Kt[1024 + lm * 32 + quad * 8];
        short8 kf3 = *(const short8*)&Kt[1536 + lm * 32 + quad * 8];
        short8 va0 = *(const short8*)&Vla[lm * 32 + quad * 8];
        short8 va1 = *(const short8*)&Vla[512 + lm * 32 + quad * 8];
        short8 vb0 = *(const short8*)&Vlb[lm * 32 + quad * 8];
        short8 vb1 = *(const short8*)&Vlb[512 + lm * 32 + quad * 8];

        #pragma unroll
        for (int qt = 0; qt < QT; qt++) {
            // chunk a: keys 0-31 of the tile (exact proven dataflow)
            float4v s0 = __builtin_amdgcn_mfma_f32_16x16x32_bf16(kf0, qf[qt], zero, 0, 0, 0);
            float4v s1 = __builtin_amdgcn_mfma_f32_16x16x32_bf16(kf1, qf[qt], zero, 0, 0, 0);
            // chunk b: keys 32-63
            float4v s2 = __builtin_amdgcn_mfma_f32_16x16x32_bf16(kf2, qf[qt], zero, 0, 0, 0);
            float4v s3 = __builtin_amdgcn_mfma_f32_16x16x32_bf16(kf3, qf[qt], zero, 0, 0, 0);
            float p0[4], p1[4], p2[4], p3[4];
            #pragma unroll
            for (int r = 0; r < 4; r++) {
                p0[r] = EXP2W(s0[r]);
                p1[r] = EXP2W(s1[r]);
                p2[r] = EXP2W(s2[r]);
                p3[r] = EXP2W(s3[r]);
            }
            uint32_t pda[4] = { pk2(p0[0], p0[1]), pk2(p0[2], p0[3]),
                                pk2(p1[0], p1[1]), pk2(p1[2], p1[3]) };
            uint32_t pdb[4] = { pk2(p2[0], p2[1]), pk2(p2[2], p2[3]),
                                pk2(p3[0], p3[1]), pk2(p3[2], p3[3]) };
            short8 pfa = *(const short8*)pda;
            short8 pfb = *(const short8*)pdb;
            accO[qt][0] = __builtin_amdgcn_mfma_f32_16x16x32_bf16(pfa, va0, accO[qt][0], 0, 0, 0);
            accO[qt][1] = __builtin_amdgcn_mfma_f32_16x16x32_bf16(pfa, va1, accO[qt][1], 0, 0, 0);
            accL[qt]    = __builtin_amdgcn_mfma_f32_16x16x32_bf16(pfa, ones, accL[qt], 0, 0, 0);
            accO[qt][0] = __builtin_amdgcn_mfma_f32_16x16x32_bf16(pfb, vb0, accO[qt][0], 0, 0, 0);
            accO[qt][1] = __builtin_amdgcn_mfma_f32_16x16x32_bf16(pfb, vb1, accO[qt][1], 0, 0, 0);
            accL[qt]    = __builtin_amdgcn_mfma_f32_16x16x32_bf16(pfb, ones, accL[qt], 0, 0, 0);
        }
    }

    // epilogue: raw partial sums (no divide); khalf 0 -> out, khalf 1 -> Opart
    float* Od = (khalf == 0) ? out : Opart;
    #pragma unroll
    for (int qt = 0; qt < QT; qt++)
        #pragma unroll
        for (int r = 0; r < 4; r++) {
            const int q = q0 + qt * 16 + quad * 4 + r;
            float* orow = Od + ((size_t)b * NSEQ + q) * DM + h * DH;
            orow[lm]      = accO[qt][0][r];
            orow[16 + lm] = accO[qt][1][r];
            if (lm == 0)
                Lp[khalf * (16 * NSEQ) + bh * NSEQ + q] = accL[qt][r];
        }
}

// ---------------------------------------------------------------------------
// Combine: out = (O0 + O1) / (L0 + L1).  2M floats, 8 per thread.
// ---------------------------------------------------------------------------
__global__ __launch_bounds__(256) void combine_kernel(
    float* __restrict__ out, const float* __restrict__ Opart,
    const float* __restrict__ Lp)
{
    const int t   = blockIdx.x * 256 + threadIdx.x;
    const size_t base = (size_t)t * 8;
    const int b   = (int)(base >> 20);                 // 4096*256 = 1M floats/batch
    const int rem = (int)(base & ((1u << 20) - 1));
    const int q   = rem >> 8;
    const int dm  = rem & 255;
    const int h   = dm >> 5;
    const int bh  = b * NHEAD + h;
    const float l0 = Lp[bh * NSEQ + q];
    const float l1 = Lp[16 * NSEQ + bh * NSEQ + q];
    const float inv = 1.0f / (l0 + l1);
    float4 a0 = *(const float4*)(out + base);
    float4 a1 = *(const float4*)(out + base + 4);
    float4 c0 = *(const float4*)(Opart + base);
    float4 c1 = *(const float4*)(Opart + base + 4);
    a0.x = (a0.x + c0.x) * inv;  a0.y = (a0.y + c0.y) * inv;
    a0.z = (a0.z + c0.z) * inv;  a0.w = (a0.w + c0.w) * inv;
    a1.x = (a1.x + c1.x) * inv;  a1.y = (a1.y + c1.y) * inv;
    a1.z = (a1.z + c1.z) * inv;  a1.w = (a1.w + c1.w) * inv;
    *(float4*)(out + base)     = a0;
    *(float4*)(out + base + 4) = a1;
}

// ---------------------------------------------------------------------------
extern "C" void kernel_launch(void* const* d_in, const int* in_sizes, int n_in,
                              void* d_out, int out_size, void* d_ws, size_t ws_size,
                              hipStream_t stream)
{
    const float* x_q  = (const float*)d_in[0];
    const float* x_kv = (const float*)d_in[1];
    const float* Wq   = (const float*)d_in[2];
    const float* bq   = (const float*)d_in[3];
    const float* Wk   = (const float*)d_in[4];
    const float* bk   = (const float*)d_in[5];
    const float* Wv   = (const float*)d_in[6];
    const float* bv   = (const float*)d_in[7];
    float* out = (float*)d_out;

    const size_t per = (size_t)BATCH * NHEAD * NSEQ * DH;  // 2M elems
    ushort_t* Qh = (ushort_t*)d_ws;
    ushort_t* Kh = Qh + per;
    ushort_t* Vt = Kh + per;
    ushort_t* Wp = (ushort_t*)d_out;   // scratch; fattn rewrites all of out

    // K-split partials live after QKV in the workspace
    const size_t qkv_bytes   = per * 3 * sizeof(ushort_t);            // 12.6 MB
    const size_t opart_elems = (size_t)BATCH * NSEQ * DM;             // 2M floats
    const size_t lp_elems    = (size_t)2 * 16 * NSEQ;                 // 128K floats
    const size_t need = qkv_bytes + (opart_elems + lp_elems) * sizeof(float);
    float* Opart = (float*)((char*)d_ws + qkv_bytes);
    float* Lp    = Opart + opart_elems;

    packw_kernel<<<96, 256, 0, stream>>>(Wq, Wk, Wv, Wp);

    dim3 pgrid(BATCH * NSEQ / 32, 3);
    proj_kernel<<<pgrid, 256, 0, stream>>>(x_q, x_kv, Wp, bq, bk, bv,
                                           Qh, Kh, Vt);

    if (ws_size >= need) {
        fattn_split_kernel<<<1024, 256, 0, stream>>>(Qh, Kh, Vt, out, Opart, Lp);
        combine_kernel<<<(BATCH * NSEQ * DM) / (256 * 8), 256, 0, stream>>>(out, Opart, Lp);
    } else {
        fattn_kernel<<<512, 256, 0, stream>>>(Qh, Kh, Vt, out);
    }
}